// Round 9
// baseline (480.228 us; speedup 1.0000x reference)
//
#include <hip/hip_runtime.h>
#include <stdint.h>

#define NA 98304
#define NT 1024
#define NC 21
#define ACH 96           // anchor chunks of 1024 (4 anchors per thread)
#define TCH 16           // target chunks of 64
#define HI_MIN 0xBF000000u   // min high-word of a valid key (iou>=0.5, bias bit)
#define NPART 64

// ws layout:
//   [0]      int    count (= n_pos, exact)
//   [64]     double neg_part[64]          (512 B)
//   [1024]   u64    tkeys[NT]   (8 KB, NOT zeroed: poison-proof keys)
//   [16384]  u64    akeys[NA]   (768 KB, NOT zeroed)
//   [802816] int    plist[NA]   (384 KB, NOT zeroed; only first `count` read)
// memset covers only [0, 576)

__device__ __forceinline__ float f0(float x) {   // focal, target=0
    const float ax = fabsf(x);
    const float u  = __expf(-ax);
    const float ce = fmaxf(x, 0.f) + __logf(1.f + u);
    const float p  = (x >= 0.f ? 1.f : u) / (1.f + u);
    return 0.75f * p * p * ce;
}
__device__ __forceinline__ float f1(float x) {   // focal, target=1
    const float ax = fabsf(x);
    const float u  = __expf(-ax);
    const float ce = fmaxf(x, 0.f) - x + __logf(1.f + u);
    const float p  = (x >= 0.f ? 1.f : u) / (1.f + u);
    const float q  = 1.f - p;
    return 0.25f * q * q * ce;
}

__device__ __forceinline__ unsigned long long mk_key(float iou, unsigned int idx) {
    return ((unsigned long long)(__float_as_uint(iou) | 0x80000000u) << 32) |
           (unsigned long long)(0xFFFFFFFFu - idx);
}

__device__ __forceinline__ void iou_iu(const float4 A, const float arA,
                                       const float4 tb, const float sa,
                                       float& inter, float& uni)
{
    const float lx = fmaxf(A.x, tb.x);
    const float ly = fmaxf(A.y, tb.y);
    const float rx = fminf(A.z, tb.z);
    const float ry = fminf(A.w, tb.w);
    const float w  = fmaxf(rx - lx, 0.f);
    const float h  = fmaxf(ry - ly, 0.f);
    inter = w * h;
    uni   = (arA + sa) - inter;
}

// ---- negative-branch focal sum: elementwise, no matching dependency ----
__global__ __launch_bounds__(256) void k_neg(
    const float4* __restrict__ preds4, double* __restrict__ neg_part)
{
    float acc = 0.f;
    const int n4 = NA * NC / 4;
    for (int i = blockIdx.x * 256 + threadIdx.x; i < n4; i += gridDim.x * 256) {
        const float4 v = preds4[i];
        acc += (f0(v.x) + f0(v.y)) + (f0(v.z) + f0(v.w));
    }
    for (int o = 32; o > 0; o >>= 1) acc += __shfl_down(acc, o);
    __shared__ float s_p[4];
    const int lane = threadIdx.x & 63, wid = threadIdx.x >> 6;
    if (lane == 0) s_p[wid] = acc;
    __syncthreads();
    if (threadIdx.x == 0)
        atomicAdd(&neg_part[blockIdx.x & (NPART - 1)],
                  (double)(s_p[0] + s_p[1] + s_p[2] + s_p[3]));
}

__global__ __launch_bounds__(256) void k_match(
    const float4* __restrict__ anchors,
    const float4* __restrict__ tboxes,
    unsigned long long* __restrict__ akeys,
    unsigned long long* __restrict__ tkeys,
    int* __restrict__ plist,
    int* __restrict__ count)
{
    __shared__ float4 s_t[64];
    __shared__ unsigned long long s_tk[64];

    const int tid   = threadIdx.x;
    const int tbase = blockIdx.y * 64;
    const int a0    = blockIdx.x * 1024 + tid;   // anchors a0, +256, +512, +768

    if (tid < 64) {
        s_t[tid]  = tboxes[tbase + tid];
        s_tk[tid] = 0ull;
    }
    const float4 A0 = anchors[a0];
    const float4 A1 = anchors[a0 + 256];
    const float4 A2 = anchors[a0 + 512];
    const float4 A3 = anchors[a0 + 768];
    __syncthreads();

    const float ar0 = (A0.z - A0.x) * (A0.w - A0.y);
    const float ar1 = (A1.z - A1.x) * (A1.w - A1.y);
    const float ar2 = (A2.z - A2.x) * (A2.w - A2.y);
    const float ar3 = (A3.z - A3.x) * (A3.w - A3.y);

    float b0 = 0.f, b1 = 0.f, b2 = 0.f, b3 = 0.f;
    int   i0 = -1,  i1 = -1,  i2 = -1,  i3 = -1;

    #pragma unroll 4
    for (int t = 0; t < 64; ++t) {
        const float4 tb = s_t[t];          // one broadcast b128 feeds 4 anchors
        const float sa = (tb.z - tb.x) * (tb.w - tb.y);

        float in0, un0, in1, un1, in2, un2, in3, un3;
        iou_iu(A0, ar0, tb, sa, in0, un0);
        iou_iu(A1, ar1, tb, sa, in1, un1);
        iou_iu(A2, ar2, tb, sa, in2, un2);
        iou_iu(A3, ar3, tb, sa, in3, un3);

        const bool h0 = (in0 + in0 >= un0);
        const bool h1 = (in1 + in1 >= un1);
        const bool h2 = (in2 + in2 >= un2);
        const bool h3 = (in3 + in3 >= un3);

        if (__builtin_expect((h0 | h1) | (h2 | h3), 0)) {
            if (h0) { const float iou = in0 / un0;
                if (iou > b0) { b0 = iou; i0 = t; }
                atomicMax(&s_tk[t], mk_key(iou, (unsigned int)a0)); }
            if (h1) { const float iou = in1 / un1;
                if (iou > b1) { b1 = iou; i1 = t; }
                atomicMax(&s_tk[t], mk_key(iou, (unsigned int)(a0 + 256))); }
            if (h2) { const float iou = in2 / un2;
                if (iou > b2) { b2 = iou; i2 = t; }
                atomicMax(&s_tk[t], mk_key(iou, (unsigned int)(a0 + 512))); }
            if (h3) { const float iou = in3 / un3;
                if (iou > b3) { b3 = iou; i3 = t; }
                atomicMax(&s_tk[t], mk_key(iou, (unsigned int)(a0 + 768))); }
        }
    }

    // flush + dedup'd append: atomicMax returns pre-value; exactly the first
    // flusher of a positive anchor sees an invalid old key -> appends once.
    if (i0 >= 0) {
        const unsigned long long old =
            atomicMax(&akeys[a0], mk_key(b0, (unsigned int)(tbase + i0)));
        if ((unsigned int)(old >> 32) < HI_MIN) plist[atomicAdd(count, 1)] = a0;
    }
    if (i1 >= 0) {
        const unsigned long long old =
            atomicMax(&akeys[a0 + 256], mk_key(b1, (unsigned int)(tbase + i1)));
        if ((unsigned int)(old >> 32) < HI_MIN) plist[atomicAdd(count, 1)] = a0 + 256;
    }
    if (i2 >= 0) {
        const unsigned long long old =
            atomicMax(&akeys[a0 + 512], mk_key(b2, (unsigned int)(tbase + i2)));
        if ((unsigned int)(old >> 32) < HI_MIN) plist[atomicAdd(count, 1)] = a0 + 512;
    }
    if (i3 >= 0) {
        const unsigned long long old =
            atomicMax(&akeys[a0 + 768], mk_key(b3, (unsigned int)(tbase + i3)));
        if ((unsigned int)(old >> 32) < HI_MIN) plist[atomicAdd(count, 1)] = a0 + 768;
    }

    __syncthreads();
    if (tid < 64) {
        const unsigned long long tk = s_tk[tid];
        if (tk != 0ull) atomicMax(&tkeys[tbase + tid], tk);
    }
}

__device__ __forceinline__ float smooth_l1(float d) {
    const float ad = fabsf(d);
    return (ad < 1.f) ? 0.5f * d * d : ad - 0.5f;
}

// one block: positive-anchor cls corrections + regression + combine
__global__ __launch_bounds__(1024) void k_final(
    const float* __restrict__ preds,
    const int* __restrict__ tlabels,
    const float4* __restrict__ anchors,
    const float4* __restrict__ tboxes,
    const float4* __restrict__ bpreds,
    const unsigned long long* __restrict__ akeys,
    const unsigned long long* __restrict__ tkeys,
    const int* __restrict__ plist,
    const int* __restrict__ count,
    const double* __restrict__ neg_part,
    float* __restrict__ out)
{
    const int tid = threadIdx.x;
    const int np  = *count;

    // cls correction: only the c==label element differs between targets 0/1
    float corr = 0.f;
    for (int i = tid; i < np; i += 1024) {
        const int a = plist[i];
        const unsigned long long k = akeys[a];      // kernel-boundary coherent
        const int lab = tlabels[0xFFFFFFFFu - (unsigned int)k];
        const float x = preds[a * NC + lab];
        corr += f1(x) - f0(x);
    }

    // regression: one target per thread
    float s = 0.f, m = 0.f;
    {
        const unsigned long long key = tkeys[tid];
        if ((unsigned int)(key >> 32) >= HI_MIN) {
            const unsigned int ga = 0xFFFFFFFFu - (unsigned int)key;
            const float4 tb  = tboxes[tid];
            const float4 abx = anchors[ga];
            const float4 pb  = bpreds[ga];
            const float bw = tb.z - tb.x, bh = tb.w - tb.y;
            const float bcx = tb.x + 0.5f * bw, bcy = tb.y + 0.5f * bh;
            const float aw = abx.z - abx.x, ah = abx.w - abx.y;
            const float acx = abx.x + 0.5f * aw, acy = abx.y + 0.5f * ah;
            const float tx = (bcx - acx) / aw;
            const float ty = (bcy - acy) / ah;
            const float tw = logf(fmaxf(bw, 1e-8f) / aw);
            const float th = logf(fmaxf(bh, 1e-8f) / ah);
            s = smooth_l1(pb.x - tx) + smooth_l1(pb.y - ty) +
                smooth_l1(pb.z - tw) + smooth_l1(pb.w - th);
            m = 1.f;
        }
    }

    for (int o = 32; o > 0; o >>= 1) {
        corr += __shfl_down(corr, o);
        s    += __shfl_down(s, o);
        m    += __shfl_down(m, o);
    }
    __shared__ float s_c[16], s_s[16], s_m[16];
    const int lane = tid & 63, wid = tid >> 6;
    if (lane == 0) { s_c[wid] = corr; s_s[wid] = s; s_m[wid] = m; }
    __syncthreads();
    if (tid == 0) {
        float rc = 0.f, rs = 0.f, rm = 0.f;
        for (int i = 0; i < 16; ++i) { rc += s_c[i]; rs += s_s[i]; rm += s_m[i]; }
        double neg = 0.0;
        for (int i = 0; i < NPART; ++i) neg += neg_part[i];
        const float cls = (float)((neg + (double)rc) / (double)np);
        const float reg = rs / (fmaxf(rm, 1.f) * 4.f);
        out[0] = cls + reg;
        out[1] = cls;
        out[2] = reg;
    }
}

extern "C" void kernel_launch(void* const* d_in, const int* in_sizes, int n_in,
                              void* d_out, int out_size, void* d_ws, size_t ws_size,
                              hipStream_t stream) {
    const float*  cls_preds = (const float*)d_in[0];
    const float4* bpreds    = (const float4*)d_in[1];
    const float4* anchors   = (const float4*)d_in[2];
    const float4* tboxes    = (const float4*)d_in[3];
    const int*    tlabels   = (const int*)d_in[4];

    char* ws = (char*)d_ws;
    int*    count    = (int*)(ws + 0);
    double* neg_part = (double*)(ws + 64);
    unsigned long long* tkeys = (unsigned long long*)(ws + 1024);
    unsigned long long* akeys = (unsigned long long*)(ws + 16384);
    int*    plist    = (int*)(ws + 802816);

    // keys/plist need NO zeroing (poison-proof encoding / count-guarded)
    hipMemsetAsync(d_ws, 0, 576, stream);

    k_neg<<<512, 256, 0, stream>>>((const float4*)cls_preds, neg_part);
    k_match<<<dim3(ACH, TCH), 256, 0, stream>>>(anchors, tboxes, akeys, tkeys,
                                                plist, count);
    k_final<<<1, 1024, 0, stream>>>(cls_preds, tlabels, anchors, tboxes, bpreds,
                                    akeys, tkeys, plist, count, neg_part,
                                    (float*)d_out);
}

// Round 10
// 140.770 us; speedup vs baseline: 3.4114x; 3.4114x over previous
//
#include <hip/hip_runtime.h>
#include <stdint.h>

#define NA 98304
#define NT 1024
#define NC 21
#define ACH 192          // anchor chunks of 512 (2 anchors per thread)
#define TCH 8            // target chunks of 128
#define HI_MIN 0xBF000000u   // min high-word of a valid key (iou>=0.5, bias bit)

// ws layout:
//   [0]     int    n_part[16]    (64 B)
//   [64]    double loss_part[64] (512 B)
//   [1024]  u64    tkeys[NT]     (8 KB, NOT zeroed: poison-proof keys)
//   [16384] u64    akeys[NA]     (768 KB, NOT zeroed)
// memset covers only [0, 576)

__device__ __forceinline__ float f0(float x) {   // focal, target=0
    const float ax = fabsf(x);
    const float u  = __expf(-ax);
    const float ce = fmaxf(x, 0.f) + __logf(1.f + u);
    const float p  = (x >= 0.f ? 1.f : u) / (1.f + u);
    return 0.75f * p * p * ce;
}
__device__ __forceinline__ float f1(float x) {   // focal, target=1
    const float ax = fabsf(x);
    const float u  = __expf(-ax);
    const float ce = fmaxf(x, 0.f) - x + __logf(1.f + u);
    const float p  = (x >= 0.f ? 1.f : u) / (1.f + u);
    const float q  = 1.f - p;
    return 0.25f * q * q * ce;
}

__device__ __forceinline__ unsigned long long mk_key(float iou, unsigned int idx) {
    // bias bit: valid keys beat 0xAA-poison and 0 under unsigned atomicMax;
    // iou ordering preserved; low word 0xFFFFFFFF-idx -> smaller index wins ties.
    return ((unsigned long long)(__float_as_uint(iou) | 0x80000000u) << 32) |
           (unsigned long long)(0xFFFFFFFFu - idx);
}

// ==== k_match: EXACT R6 structure (measured 63 us), poison-proof keys ====
__global__ __launch_bounds__(256) void k_match(
    const float4* __restrict__ anchors,
    const float4* __restrict__ tboxes,
    unsigned long long* __restrict__ akeys,
    unsigned long long* __restrict__ tkeys)
{
    __shared__ float4 s_t[128];
    __shared__ unsigned long long s_tk[128];

    const int tid   = threadIdx.x;
    const int tbase = blockIdx.y * 128;
    const int a0    = blockIdx.x * 512 + tid;
    const int a1    = a0 + 256;

    if (tid < 128) {
        s_t[tid]  = tboxes[tbase + tid];
        s_tk[tid] = 0ull;
    }
    const float4 A0 = anchors[a0];
    const float4 A1 = anchors[a1];
    __syncthreads();

    const float ar0 = (A0.z - A0.x) * (A0.w - A0.y);
    const float ar1 = (A1.z - A1.x) * (A1.w - A1.y);

    float b0 = 0.f, b1 = 0.f;
    int   i0 = -1,  i1 = -1;

    #pragma unroll 4
    for (int t = 0; t < 128; ++t) {
        const float4 tb = s_t[t];          // one broadcast b128, shared by 2 anchors
        const float sa = (tb.z - tb.x) * (tb.w - tb.y);

        {
            const float lx = fmaxf(A0.x, tb.x);
            const float ly = fmaxf(A0.y, tb.y);
            const float rx = fminf(A0.z, tb.z);
            const float ry = fminf(A0.w, tb.w);
            const float w  = fmaxf(rx - lx, 0.f);
            const float h  = fmaxf(ry - ly, 0.f);
            const float inter = w * h;
            const float uni = (ar0 + sa) - inter;
            if (__builtin_expect(inter + inter >= uni, 0)) {
                const float iou = inter / uni;
                if (iou > b0) { b0 = iou; i0 = t; }
                atomicMax(&s_tk[t], mk_key(iou, (unsigned int)a0));
            }
        }
        {
            const float lx = fmaxf(A1.x, tb.x);
            const float ly = fmaxf(A1.y, tb.y);
            const float rx = fminf(A1.z, tb.z);
            const float ry = fminf(A1.w, tb.w);
            const float w  = fmaxf(rx - lx, 0.f);
            const float h  = fmaxf(ry - ly, 0.f);
            const float inter = w * h;
            const float uni = (ar1 + sa) - inter;
            if (__builtin_expect(inter + inter >= uni, 0)) {
                const float iou = inter / uni;
                if (iou > b1) { b1 = iou; i1 = t; }
                atomicMax(&s_tk[t], mk_key(iou, (unsigned int)a1));
            }
        }
    }

    // fire-and-forget flushes ONLY (no return-value dependence — R9 lesson)
    if (i0 >= 0) atomicMax(&akeys[a0], mk_key(b0, (unsigned int)(tbase + i0)));
    if (i1 >= 0) atomicMax(&akeys[a1], mk_key(b1, (unsigned int)(tbase + i1)));

    __syncthreads();
    if (tid < 128) {
        const unsigned long long tk = s_tk[tid];
        if (tk != 0ull) atomicMax(&tkeys[tbase + tid], tk);
    }
}

// ==== k_cls: f0 over all elems + per-positive correction; spread partials ====
// 768 blocks x 256 threads, 128 anchors/block.
__global__ __launch_bounds__(256) void k_cls(
    const float4* __restrict__ preds4,
    const float* __restrict__ preds,
    const int* __restrict__ tlabels,
    const unsigned long long* __restrict__ akeys,
    double* __restrict__ loss_part,
    int* __restrict__ n_part)
{
    __shared__ float s_red[4];
    __shared__ int   s_cnt[2];

    const int tid = threadIdx.x;
    const int blk = blockIdx.x;

    float acc = 0.f;

    // corrections + n_pos from this block's 128 anchor keys (kernel-boundary
    // coherent plain loads; valid iff biased high word >= HI_MIN)
    bool valid = false;
    if (tid < 128) {
        const unsigned long long k = akeys[blk * 128 + tid];
        if ((unsigned int)(k >> 32) >= HI_MIN) {
            valid = true;
            const int lab = tlabels[0xFFFFFFFFu - (unsigned int)k];
            const float x = preds[(blk * 128 + tid) * NC + lab];
            acc += f1(x) - f0(x);
        }
    }
    const unsigned long long bal = __ballot(valid);   // waves 2,3 contribute 0

    // negative-branch focal over this block's 128*21 = 2688 floats (672 float4)
    const int pbase = blk * 672;
    #pragma unroll
    for (int j = 0; j < 3; ++j) {
        const int i = tid + j * 256;
        if (i < 672) {
            const float4 v = preds4[pbase + i];
            acc += (f0(v.x) + f0(v.y)) + (f0(v.z) + f0(v.w));
        }
    }

    for (int o = 32; o > 0; o >>= 1) acc += __shfl_down(acc, o);
    const int lane = tid & 63, wid = tid >> 6;
    if (lane == 0) {
        s_red[wid] = acc;
        if (wid < 2) s_cnt[wid] = (int)__popcll(bal);
    }
    __syncthreads();
    if (tid == 0) {
        atomicAdd(&loss_part[blk & 63],
                  (double)(s_red[0] + s_red[1] + s_red[2] + s_red[3]));
        atomicAdd(&n_part[blk & 15], s_cnt[0] + s_cnt[1]);
    }
}

__device__ __forceinline__ float smooth_l1(float d) {
    const float ad = fabsf(d);
    return (ad < 1.f) ? 0.5f * d * d : ad - 0.5f;
}

// ==== k_final: one block — regression + combine ====
__global__ __launch_bounds__(1024) void k_final(
    const float4* __restrict__ anchors,
    const float4* __restrict__ tboxes,
    const float4* __restrict__ bpreds,
    const unsigned long long* __restrict__ tkeys,
    const double* __restrict__ loss_part,
    const int* __restrict__ n_part,
    float* __restrict__ out)
{
    const int tid = threadIdx.x;

    float s = 0.f, m = 0.f;
    {
        const unsigned long long key = tkeys[tid];
        if ((unsigned int)(key >> 32) >= HI_MIN) {
            const unsigned int ga = 0xFFFFFFFFu - (unsigned int)key;
            const float4 tb  = tboxes[tid];
            const float4 abx = anchors[ga];
            const float4 pb  = bpreds[ga];
            const float bw = tb.z - tb.x, bh = tb.w - tb.y;
            const float bcx = tb.x + 0.5f * bw, bcy = tb.y + 0.5f * bh;
            const float aw = abx.z - abx.x, ah = abx.w - abx.y;
            const float acx = abx.x + 0.5f * aw, acy = abx.y + 0.5f * ah;
            const float tx = (bcx - acx) / aw;
            const float ty = (bcy - acy) / ah;
            const float tw = logf(fmaxf(bw, 1e-8f) / aw);
            const float th = logf(fmaxf(bh, 1e-8f) / ah);
            s = smooth_l1(pb.x - tx) + smooth_l1(pb.y - ty) +
                smooth_l1(pb.z - tw) + smooth_l1(pb.w - th);
            m = 1.f;
        }
    }
    for (int o = 32; o > 0; o >>= 1) {
        s += __shfl_down(s, o);
        m += __shfl_down(m, o);
    }
    __shared__ float s_s[16], s_m[16];
    const int lane = tid & 63, wid = tid >> 6;
    if (lane == 0) { s_s[wid] = s; s_m[wid] = m; }
    __syncthreads();
    if (tid == 0) {
        float rs = 0.f, rm = 0.f;
        for (int i = 0; i < 16; ++i) { rs += s_s[i]; rm += s_m[i]; }
        double cl = 0.0;
        for (int i = 0; i < 64; ++i) cl += loss_part[i];
        int np = 0;
        for (int i = 0; i < 16; ++i) np += n_part[i];
        const float cls = (float)(cl / (double)np);
        const float reg = rs / (fmaxf(rm, 1.f) * 4.f);
        out[0] = cls + reg;
        out[1] = cls;
        out[2] = reg;
    }
}

extern "C" void kernel_launch(void* const* d_in, const int* in_sizes, int n_in,
                              void* d_out, int out_size, void* d_ws, size_t ws_size,
                              hipStream_t stream) {
    const float*  cls_preds = (const float*)d_in[0];
    const float4* bpreds    = (const float4*)d_in[1];
    const float4* anchors   = (const float4*)d_in[2];
    const float4* tboxes    = (const float4*)d_in[3];
    const int*    tlabels   = (const int*)d_in[4];

    char* ws = (char*)d_ws;
    int*    n_part    = (int*)(ws + 0);
    double* loss_part = (double*)(ws + 64);
    unsigned long long* tkeys = (unsigned long long*)(ws + 1024);
    unsigned long long* akeys = (unsigned long long*)(ws + 16384);

    // keys need NO zeroing (poison-proof encoding); only 576-B header
    hipMemsetAsync(d_ws, 0, 576, stream);

    k_match<<<dim3(ACH, TCH), 256, 0, stream>>>(anchors, tboxes, akeys, tkeys);
    k_cls<<<NA / 128, 256, 0, stream>>>((const float4*)cls_preds, cls_preds,
                                        tlabels, akeys, loss_part, n_part);
    k_final<<<1, 1024, 0, stream>>>(anchors, tboxes, bpreds, tkeys,
                                    loss_part, n_part, (float*)d_out);
}

// Round 12
// 138.208 us; speedup vs baseline: 3.4747x; 1.0185x over previous
//
#include <hip/hip_runtime.h>
#include <stdint.h>

#define NA 98304
#define NT 1024
#define NC 21
#define ACH 192          // anchor chunks of 512 (2 anchors per thread)
#define TCH 8            // target chunks of 128
#define NBLK (ACH * TCH) // 1536
#define EPB  256         // epilogue blocks
#define HI_MIN 0xBF000000u   // min high-word of a valid key (iou>=0.5, bias bit)

// ws layout:
//   [0]     int    done                (zeroed by k_match block (0,0))
//   [64]    double loss_part[64]       (512 B, zeroed by k_match block (0,0))
//   [576]   int    n_part[16]          (64 B,  zeroed by k_match block (0,0))
//   [1024]  float  f0_part[NBLK]       (6 KB, unique-slot stores, no zeroing)
//   [8192]  u64    tkeys[NT]           (8 KB, NOT zeroed: poison-proof keys)
//   [16384] u64    akeys[NA]           (768 KB, NOT zeroed)
// NO memset node.

__device__ __forceinline__ float f0(float x) {   // focal, target=0
    const float ax = fabsf(x);
    const float u  = __expf(-ax);
    const float ce = fmaxf(x, 0.f) + __logf(1.f + u);
    const float p  = (x >= 0.f ? 1.f : u) / (1.f + u);
    return 0.75f * p * p * ce;
}
__device__ __forceinline__ float f1(float x) {   // focal, target=1
    const float ax = fabsf(x);
    const float u  = __expf(-ax);
    const float ce = fmaxf(x, 0.f) - x + __logf(1.f + u);
    const float p  = (x >= 0.f ? 1.f : u) / (1.f + u);
    const float q  = 1.f - p;
    return 0.25f * q * q * ce;
}
__device__ __forceinline__ unsigned long long mk_key(float iou, unsigned int idx) {
    // bias bit: valid keys beat 0xAA-poison and 0 under unsigned atomicMax;
    // iou ordering preserved; low word 0xFFFFFFFF-idx -> smaller index wins ties.
    return ((unsigned long long)(__float_as_uint(iou) | 0x80000000u) << 32) |
           (unsigned long long)(0xFFFFFFFFu - idx);
}
__device__ __forceinline__ float smooth_l1(float d) {
    const float ad = fabsf(d);
    return (ad < 1.f) ? 0.5f * d * d : ad - 0.5f;
}

// ==== node 1: R10-proven match + f0 slice + header zero ====
__global__ __launch_bounds__(256) void k_match(
    const float4* __restrict__ anchors,
    const float4* __restrict__ tboxes,
    const float4* __restrict__ preds4,
    unsigned long long* __restrict__ akeys,
    unsigned long long* __restrict__ tkeys,
    float* __restrict__ f0_part,
    unsigned* __restrict__ hdr)
{
    __shared__ float4 s_t[128];
    __shared__ unsigned long long s_tk[128];
    __shared__ float s_f[4];

    const int tid   = threadIdx.x;
    const int L     = blockIdx.y * ACH + blockIdx.x;
    const int tbase = blockIdx.y * 128;
    const int a0    = blockIdx.x * 512 + tid;
    const int a1    = a0 + 256;

    // header zero: 640 B = 160 words (done + loss_part + n_part); node-2-only data
    if (L == 0 && tid < 160) hdr[tid] = 0u;

    if (tid < 128) {
        s_t[tid]  = tboxes[tbase + tid];
        s_tk[tid] = 0ull;
    }
    const float4 A0 = anchors[a0];
    const float4 A1 = anchors[a1];

    // f0 over this block's contiguous 336-float4 slice of preds (no match dep)
    float facc;
    {
        const int pb = L * 336;
        const float4 v0 = preds4[pb + tid];
        facc = (f0(v0.x) + f0(v0.y)) + (f0(v0.z) + f0(v0.w));
        if (tid < 80) {
            const float4 v1 = preds4[pb + 256 + tid];
            facc += (f0(v1.x) + f0(v1.y)) + (f0(v1.z) + f0(v1.w));
        }
    }
    __syncthreads();

    const float ar0 = (A0.z - A0.x) * (A0.w - A0.y);
    const float ar1 = (A1.z - A1.x) * (A1.w - A1.y);

    float b0 = 0.f, b1 = 0.f;
    int   i0 = -1,  i1 = -1;

    #pragma unroll 4
    for (int t = 0; t < 128; ++t) {
        const float4 tb = s_t[t];          // one broadcast b128, shared by 2 anchors
        const float sa = (tb.z - tb.x) * (tb.w - tb.y);
        {
            const float lx = fmaxf(A0.x, tb.x);
            const float ly = fmaxf(A0.y, tb.y);
            const float rx = fminf(A0.z, tb.z);
            const float ry = fminf(A0.w, tb.w);
            const float w  = fmaxf(rx - lx, 0.f);
            const float h  = fmaxf(ry - ly, 0.f);
            const float inter = w * h;
            const float uni = (ar0 + sa) - inter;
            if (__builtin_expect(inter + inter >= uni, 0)) {
                const float iou = inter / uni;   // exact div = reference rounding
                if (iou > b0) { b0 = iou; i0 = t; }
                atomicMax(&s_tk[t], mk_key(iou, (unsigned int)a0));
            }
        }
        {
            const float lx = fmaxf(A1.x, tb.x);
            const float ly = fmaxf(A1.y, tb.y);
            const float rx = fminf(A1.z, tb.z);
            const float ry = fminf(A1.w, tb.w);
            const float w  = fmaxf(rx - lx, 0.f);
            const float h  = fmaxf(ry - ly, 0.f);
            const float inter = w * h;
            const float uni = (ar1 + sa) - inter;
            if (__builtin_expect(inter + inter >= uni, 0)) {
                const float iou = inter / uni;
                if (iou > b1) { b1 = iou; i1 = t; }
                atomicMax(&s_tk[t], mk_key(iou, (unsigned int)a1));
            }
        }
    }

    // fire-and-forget flushes ONLY (no return-value dependence — R9 lesson)
    if (i0 >= 0) atomicMax(&akeys[a0], mk_key(b0, (unsigned int)(tbase + i0)));
    if (i1 >= 0) atomicMax(&akeys[a1], mk_key(b1, (unsigned int)(tbase + i1)));

    // f0 block-reduce -> unique slot (plain store, read only in node 2)
    for (int o = 32; o > 0; o >>= 1) facc += __shfl_down(facc, o);
    const int lane = tid & 63, wid = tid >> 6;
    if (lane == 0) s_f[wid] = facc;

    __syncthreads();
    if (tid < 128) {
        const unsigned long long tk = s_tk[tid];
        if (tk != 0ull) atomicMax(&tkeys[tbase + tid], tk);
    }
    if (tid == 0) f0_part[L] = s_f[0] + s_f[1] + s_f[2] + s_f[3];
}

// ==== node 2: corrections + partials + done-counter finale ====
__global__ __launch_bounds__(256) void k_epi(
    const float* __restrict__ preds,
    const int* __restrict__ tlabels,
    const float4* __restrict__ anchors,
    const float4* __restrict__ tboxes,
    const float4* __restrict__ bpreds,
    const unsigned long long* __restrict__ akeys,
    const unsigned long long* __restrict__ tkeys,
    const float* __restrict__ f0_part,
    double* __restrict__ loss_part,
    int* __restrict__ n_part,
    int* __restrict__ done,
    float* __restrict__ out)
{
    __shared__ float s_red[4];
    __shared__ int   s_cnt[4];
    __shared__ int   s_flag;
    __shared__ float s_s[4], s_m[4];
    __shared__ double s_dbl[64];
    __shared__ int    s_int[16];

    const int tid = threadIdx.x;
    const int blk = blockIdx.x;
    const int lane = tid & 63, wid = tid >> 6;

    // corrections for this block's 384 anchors (keys coherent across node boundary)
    float acc = 0.f;
    int   cnt = 0;
    {
        const int a = blk * 384 + tid;
        const unsigned long long k = akeys[a];
        if ((unsigned int)(k >> 32) >= HI_MIN) {
            cnt = 1;
            const int lab = tlabels[0xFFFFFFFFu - (unsigned int)k];
            acc += f1(preds[a * NC + lab]) - f0(preds[a * NC + lab]);
        }
    }
    if (tid < 128) {
        const int a = blk * 384 + 256 + tid;
        const unsigned long long k = akeys[a];
        if ((unsigned int)(k >> 32) >= HI_MIN) {
            cnt += 1;
            const int lab = tlabels[0xFFFFFFFFu - (unsigned int)k];
            acc += f1(preds[a * NC + lab]) - f0(preds[a * NC + lab]);
        }
    }
    // fold in this block's 6 f0 partials (plain loads, node boundary coherent)
    if (tid < 6) acc += f0_part[blk * 6 + tid];

    for (int o = 32; o > 0; o >>= 1) {
        acc += __shfl_down(acc, o);
        cnt += __shfl_down(cnt, o);
    }
    if (lane == 0) { s_red[wid] = acc; s_cnt[wid] = cnt; }
    __syncthreads();
    if (tid == 0) {
        atomicAdd(&loss_part[blk & 63],
                  (double)(s_red[0] + s_red[1] + s_red[2] + s_red[3]));
        atomicAdd(&n_part[blk & 15], s_cnt[0] + s_cnt[1] + s_cnt[2] + s_cnt[3]);
        __threadfence();                       // partials visible before counter
        s_flag = (atomicAdd(done, 1) == EPB - 1);
    }
    __syncthreads();
    if (!s_flag) return;

    // ---- last block: regression over 1024 targets + combine ----
    float s = 0.f, m = 0.f;
    #pragma unroll
    for (int j = 0; j < 4; ++j) {
        const int t = tid + 256 * j;
        const unsigned long long key = tkeys[t];   // node-boundary coherent
        if ((unsigned int)(key >> 32) >= HI_MIN) {
            const unsigned int ga = 0xFFFFFFFFu - (unsigned int)key;
            const float4 tb  = tboxes[t];
            const float4 abx = anchors[ga];
            const float4 pb  = bpreds[ga];
            const float bw = tb.z - tb.x, bh = tb.w - tb.y;
            const float bcx = tb.x + 0.5f * bw, bcy = tb.y + 0.5f * bh;
            const float aw = abx.z - abx.x, ah = abx.w - abx.y;
            const float acx = abx.x + 0.5f * aw, acy = abx.y + 0.5f * ah;
            const float tx = (bcx - acx) / aw;
            const float ty = (bcy - acy) / ah;
            const float tw = logf(fmaxf(bw, 1e-8f) / aw);
            const float th = logf(fmaxf(bh, 1e-8f) / ah);
            s += smooth_l1(pb.x - tx) + smooth_l1(pb.y - ty) +
                 smooth_l1(pb.z - tw) + smooth_l1(pb.w - th);
            m += 1.f;
        }
    }
    for (int o = 32; o > 0; o >>= 1) {
        s += __shfl_down(s, o);
        m += __shfl_down(m, o);
    }
    __syncthreads();          // s_red/s_cnt reuse done
    if (lane == 0) { s_s[wid] = s; s_m[wid] = m; }

    // coherent atomic reads of the spread partials (written by other XCDs)
    if (tid < 64) s_dbl[tid] = atomicAdd(&loss_part[tid], 0.0);
    if (tid >= 64 && tid < 80) s_int[tid - 64] = atomicAdd(&n_part[tid - 64], 0);
    __syncthreads();
    if (tid == 0) {
        double cl = 0.0;
        for (int i = 0; i < 64; ++i) cl += s_dbl[i];
        int np = 0;
        for (int i = 0; i < 16; ++i) np += s_int[i];
        const float rs = s_s[0] + s_s[1] + s_s[2] + s_s[3];
        const float rm = s_m[0] + s_m[1] + s_m[2] + s_m[3];
        const float cls = (float)(cl / (double)np);
        const float reg = rs / (fmaxf(rm, 1.f) * 4.f);
        out[0] = cls + reg;
        out[1] = cls;
        out[2] = reg;
    }
}

extern "C" void kernel_launch(void* const* d_in, const int* in_sizes, int n_in,
                              void* d_out, int out_size, void* d_ws, size_t ws_size,
                              hipStream_t stream) {
    const float*  preds   = (const float*)d_in[0];
    const float4* preds4  = (const float4*)d_in[0];
    const float4* bpreds  = (const float4*)d_in[1];
    const float4* anchors = (const float4*)d_in[2];
    const float4* tboxes  = (const float4*)d_in[3];
    const int*    tlabels = (const int*)d_in[4];

    char* ws = (char*)d_ws;
    int*    done      = (int*)(ws + 0);
    double* loss_part = (double*)(ws + 64);
    int*    n_part    = (int*)(ws + 576);
    float*  f0_part   = (float*)(ws + 1024);
    unsigned long long* tkeys = (unsigned long long*)(ws + 8192);
    unsigned long long* akeys = (unsigned long long*)(ws + 16384);

    k_match<<<dim3(ACH, TCH), 256, 0, stream>>>(anchors, tboxes, preds4,
                                                akeys, tkeys, f0_part,
                                                (unsigned*)d_ws);
    k_epi<<<EPB, 256, 0, stream>>>(preds, tlabels, anchors, tboxes, bpreds,
                                   akeys, tkeys, f0_part, loss_part, n_part,
                                   done, (float*)d_out);
}

// Round 13
// 136.818 us; speedup vs baseline: 3.5100x; 1.0102x over previous
//
#include <hip/hip_runtime.h>
#include <stdint.h>

#define NA 98304
#define NT 1024
#define NC 21
#define ACH 192          // anchor chunks of 512 (2 anchors per thread)
#define TCH 8            // target chunks of 128
#define NBLK (ACH * TCH) // 1536
#define HI_MIN 0xBF000000u   // min high-word of a valid key (iou>=0.5, bias bit)

// ws layout:
//   [0]     int   done2                 (zeroed by memset)
//   [64]    int   done_ac[192]          (768 B, zeroed by memset)
//   [1024]  float f0_part[NBLK]         (6 KB, unique-slot atomicExch)
//   [7168]  float corr_part[192]        (768 B, unique-slot atomicExch)
//   [7936]  int   npos_part[192]        (768 B, unique-slot atomicExch)
//   [12288] u64   tkeys[NT]             (8 KB, NOT zeroed: poison-proof keys)
//   [20480] u64   akeys[NA]             (768 KB, NOT zeroed)
// memset covers only [0, 1024)

__device__ __forceinline__ float f0(float x) {   // focal, target=0
    const float ax = fabsf(x);
    const float u  = __expf(-ax);
    const float ce = fmaxf(x, 0.f) + __logf(1.f + u);
    const float p  = (x >= 0.f ? 1.f : u) / (1.f + u);
    return 0.75f * p * p * ce;
}
__device__ __forceinline__ float f1(float x) {   // focal, target=1
    const float ax = fabsf(x);
    const float u  = __expf(-ax);
    const float ce = fmaxf(x, 0.f) - x + __logf(1.f + u);
    const float p  = (x >= 0.f ? 1.f : u) / (1.f + u);
    const float q  = 1.f - p;
    return 0.25f * q * q * ce;
}
__device__ __forceinline__ unsigned long long mk_key(float iou, unsigned int idx) {
    // bias bit: valid keys beat 0xAA-poison and 0 under unsigned atomicMax;
    // iou ordering preserved; low word 0xFFFFFFFF-idx -> smaller index wins ties.
    return ((unsigned long long)(__float_as_uint(iou) | 0x80000000u) << 32) |
           (unsigned long long)(0xFFFFFFFFu - idx);
}
__device__ __forceinline__ float smooth_l1(float d) {
    const float ad = fabsf(d);
    return (ad < 1.f) ? 0.5f * d * d : ad - 0.5f;
}

__global__ __launch_bounds__(256) void k_all(
    const float* __restrict__ preds,
    const float4* __restrict__ preds4,
    const int* __restrict__ tlabels,
    const float4* __restrict__ anchors,
    const float4* __restrict__ tboxes,
    const float4* __restrict__ bpreds,
    unsigned long long* __restrict__ akeys,
    unsigned long long* __restrict__ tkeys,
    float* __restrict__ f0_part,
    float* __restrict__ corr_part,
    int* __restrict__ npos_part,
    int* __restrict__ done_ac,
    int* __restrict__ done2,
    float* __restrict__ out)
{
    __shared__ float4 s_t[128];
    __shared__ unsigned long long s_tk[128];
    __shared__ float s_f[4];
    __shared__ int   s_last, s_fin;
    __shared__ float s_a[4];
    __shared__ int   s_c[4];
    __shared__ double s_d[4];
    __shared__ int    s_i[4];
    __shared__ float  s_s[4], s_m[4];

    const int tid   = threadIdx.x;
    const int ac    = blockIdx.x;
    const int L     = blockIdx.y * ACH + ac;
    const int tbase = blockIdx.y * 128;
    const int a0    = ac * 512 + tid;
    const int a1    = a0 + 256;
    const int lane  = tid & 63, wid = tid >> 6;

    // ================= PHASE A: match (R10/R12-proven) + f0 slice =============
    if (tid < 128) {
        s_t[tid]  = tboxes[tbase + tid];
        s_tk[tid] = 0ull;
    }
    const float4 A0 = anchors[a0];
    const float4 A1 = anchors[a1];

    // f0 over this block's contiguous 336-float4 slice of preds (no match dep)
    float facc;
    {
        const int pb = L * 336;
        const float4 v0 = preds4[pb + tid];
        facc = (f0(v0.x) + f0(v0.y)) + (f0(v0.z) + f0(v0.w));
        if (tid < 80) {
            const float4 v1 = preds4[pb + 256 + tid];
            facc += (f0(v1.x) + f0(v1.y)) + (f0(v1.z) + f0(v1.w));
        }
    }
    __syncthreads();

    const float ar0 = (A0.z - A0.x) * (A0.w - A0.y);
    const float ar1 = (A1.z - A1.x) * (A1.w - A1.y);

    float b0 = 0.f, b1 = 0.f;
    int   i0 = -1,  i1 = -1;

    #pragma unroll 4
    for (int t = 0; t < 128; ++t) {
        const float4 tb = s_t[t];          // one broadcast b128, shared by 2 anchors
        const float sa = (tb.z - tb.x) * (tb.w - tb.y);
        {
            const float lx = fmaxf(A0.x, tb.x);
            const float ly = fmaxf(A0.y, tb.y);
            const float rx = fminf(A0.z, tb.z);
            const float ry = fminf(A0.w, tb.w);
            const float w  = fmaxf(rx - lx, 0.f);
            const float h  = fmaxf(ry - ly, 0.f);
            const float inter = w * h;
            const float uni = (ar0 + sa) - inter;
            if (__builtin_expect(inter + inter >= uni, 0)) {
                const float iou = inter / uni;   // exact div = reference rounding
                if (iou > b0) { b0 = iou; i0 = t; }
                atomicMax(&s_tk[t], mk_key(iou, (unsigned int)a0));
            }
        }
        {
            const float lx = fmaxf(A1.x, tb.x);
            const float ly = fmaxf(A1.y, tb.y);
            const float rx = fminf(A1.z, tb.z);
            const float ry = fminf(A1.w, tb.w);
            const float w  = fmaxf(rx - lx, 0.f);
            const float h  = fmaxf(ry - ly, 0.f);
            const float inter = w * h;
            const float uni = (ar1 + sa) - inter;
            if (__builtin_expect(inter + inter >= uni, 0)) {
                const float iou = inter / uni;
                if (iou > b1) { b1 = iou; i1 = t; }
                atomicMax(&s_tk[t], mk_key(iou, (unsigned int)a1));
            }
        }
    }

    // fire-and-forget flushes ONLY (no return-value dependence — R9 lesson)
    if (i0 >= 0) atomicMax(&akeys[a0], mk_key(b0, (unsigned int)(tbase + i0)));
    if (i1 >= 0) atomicMax(&akeys[a1], mk_key(b1, (unsigned int)(tbase + i1)));

    for (int o = 32; o > 0; o >>= 1) facc += __shfl_down(facc, o);
    if (lane == 0) s_f[wid] = facc;

    __syncthreads();
    if (tid < 128) {
        const unsigned long long tk = s_tk[tid];
        if (tk != 0ull) atomicMax(&tkeys[tbase + tid], tk);
    }
    if (tid == 0)   // unique slot, device-scope atomic store
        atomicExch(&f0_part[L], s_f[0] + s_f[1] + s_f[2] + s_f[3]);

    // barrier drains vmcnt: this block's key flushes complete before counter bump
    __syncthreads();
    if (tid == 0) {
        __threadfence();
        s_last = (atomicAdd(&done_ac[ac], 1) == TCH - 1);
    }
    __syncthreads();
    if (!s_last) return;

    // ============ PHASE B (192 completers): corrections for 512 anchors =======
    float acc = 0.f;
    int   cnt = 0;
    {
        const unsigned long long k = atomicMax(&akeys[a0], 0ull);  // coherent read
        if ((unsigned int)(k >> 32) >= HI_MIN) {
            cnt = 1;
            const int lab = tlabels[0xFFFFFFFFu - (unsigned int)k];
            const float x = preds[a0 * NC + lab];
            acc += f1(x) - f0(x);
        }
    }
    {
        const unsigned long long k = atomicMax(&akeys[a1], 0ull);
        if ((unsigned int)(k >> 32) >= HI_MIN) {
            cnt += 1;
            const int lab = tlabels[0xFFFFFFFFu - (unsigned int)k];
            const float x = preds[a1 * NC + lab];
            acc += f1(x) - f0(x);
        }
    }
    // fold the 8 f0 slices of this ac (written + fenced before done_ac bumps)
    if (tid < TCH) acc += atomicAdd(&f0_part[ac + tid * ACH], 0.f);

    for (int o = 32; o > 0; o >>= 1) {
        acc += __shfl_down(acc, o);
        cnt += __shfl_down(cnt, o);
    }
    if (lane == 0) { s_a[wid] = acc; s_c[wid] = cnt; }
    __syncthreads();
    if (tid == 0) {
        atomicExch(&corr_part[ac], s_a[0] + s_a[1] + s_a[2] + s_a[3]);
        atomicExch(&npos_part[ac], s_c[0] + s_c[1] + s_c[2] + s_c[3]);
        __threadfence();
        s_fin = (atomicAdd(done2, 1) == ACH - 1);
    }
    __syncthreads();
    if (!s_fin) return;

    // ============ PHASE C (last completer): regression + combine ==============
    double cl = 0.0;
    int    np = 0;
    if (tid < ACH) {
        cl = (double)atomicAdd(&corr_part[tid], 0.f);   // coherent reads
        np = atomicAdd(&npos_part[tid], 0);
    }
    float s = 0.f, m = 0.f;
    #pragma unroll
    for (int j = 0; j < 4; ++j) {
        const int t = tid + 256 * j;
        const unsigned long long key = atomicMax(&tkeys[t], 0ull);
        if ((unsigned int)(key >> 32) >= HI_MIN) {
            const unsigned int ga = 0xFFFFFFFFu - (unsigned int)key;
            const float4 tb  = tboxes[t];
            const float4 abx = anchors[ga];
            const float4 pb  = bpreds[ga];
            const float bw = tb.z - tb.x, bh = tb.w - tb.y;
            const float bcx = tb.x + 0.5f * bw, bcy = tb.y + 0.5f * bh;
            const float aw = abx.z - abx.x, ah = abx.w - abx.y;
            const float acx = abx.x + 0.5f * aw, acy = abx.y + 0.5f * ah;
            const float tx = (bcx - acx) / aw;
            const float ty = (bcy - acy) / ah;
            const float tw = logf(fmaxf(bw, 1e-8f) / aw);
            const float th = logf(fmaxf(bh, 1e-8f) / ah);
            s += smooth_l1(pb.x - tx) + smooth_l1(pb.y - ty) +
                 smooth_l1(pb.z - tw) + smooth_l1(pb.w - th);
            m += 1.f;
        }
    }
    for (int o = 32; o > 0; o >>= 1) {
        cl += __shfl_down(cl, o);
        np += __shfl_down(np, o);
        s  += __shfl_down(s, o);
        m  += __shfl_down(m, o);
    }
    __syncthreads();
    if (lane == 0) { s_d[wid] = cl; s_i[wid] = np; s_s[wid] = s; s_m[wid] = m; }
    __syncthreads();
    if (tid == 0) {
        const double cls_sum = s_d[0] + s_d[1] + s_d[2] + s_d[3];
        const int    npos    = s_i[0] + s_i[1] + s_i[2] + s_i[3];
        const float  rs      = s_s[0] + s_s[1] + s_s[2] + s_s[3];
        const float  rm      = s_m[0] + s_m[1] + s_m[2] + s_m[3];
        const float cls = (float)(cls_sum / (double)npos);
        const float reg = rs / (fmaxf(rm, 1.f) * 4.f);
        out[0] = cls + reg;
        out[1] = cls;
        out[2] = reg;
    }
}

extern "C" void kernel_launch(void* const* d_in, const int* in_sizes, int n_in,
                              void* d_out, int out_size, void* d_ws, size_t ws_size,
                              hipStream_t stream) {
    const float*  preds   = (const float*)d_in[0];
    const float4* preds4  = (const float4*)d_in[0];
    const float4* bpreds  = (const float4*)d_in[1];
    const float4* anchors = (const float4*)d_in[2];
    const float4* tboxes  = (const float4*)d_in[3];
    const int*    tlabels = (const int*)d_in[4];

    char* ws = (char*)d_ws;
    int*    done2     = (int*)(ws + 0);
    int*    done_ac   = (int*)(ws + 64);
    float*  f0_part   = (float*)(ws + 1024);
    float*  corr_part = (float*)(ws + 7168);
    int*    npos_part = (int*)(ws + 7936);
    unsigned long long* tkeys = (unsigned long long*)(ws + 12288);
    unsigned long long* akeys = (unsigned long long*)(ws + 20480);

    // only the done counters need zeroing (everything else unique-slot/poison-proof)
    hipMemsetAsync(d_ws, 0, 1024, stream);

    k_all<<<dim3(ACH, TCH), 256, 0, stream>>>(
        preds, preds4, tlabels, anchors, tboxes, bpreds,
        akeys, tkeys, f0_part, corr_part, npos_part,
        done_ac, done2, (float*)d_out);
}